// Round 1
// baseline (265.622 us; speedup 1.0000x reference)
//
#include <hip/hip_runtime.h>

#define NUM_CLASSES 21
#define HW (512 * 512)
#define NBATCH 8
#define TOTAL_PIX (NBATCH * HW)
#define SMOOTH 1e-6f

// counts layout in d_ws (unsigned int):
//  [0 .. 20]   cnt_pred
//  [21 .. 41]  cnt_tgt
//  [42 .. 62]  inter

__global__ void iou_hist_kernel(const float* __restrict__ pred,
                                const int* __restrict__ target,
                                unsigned int* __restrict__ counts) {
    __shared__ unsigned int s_pred[NUM_CLASSES];
    __shared__ unsigned int s_tgt[NUM_CLASSES];
    __shared__ unsigned int s_inter[NUM_CLASSES];

    const int tid = threadIdx.x;
    if (tid < NUM_CLASSES) {
        s_pred[tid] = 0u;
        s_tgt[tid] = 0u;
        s_inter[tid] = 0u;
    }
    __syncthreads();

    const int nquads = TOTAL_PIX / 4;  // 524288
    const int stride = gridDim.x * blockDim.x;

    for (int q = blockIdx.x * blockDim.x + tid; q < nquads; q += stride) {
        const int p = q * 4;           // base pixel (all 4 in same image: HW % 4 == 0)
        const int b = p / HW;
        const int i = p - b * HW;
        const float* base = pred + (size_t)b * NUM_CLASSES * HW + i;

        float4 v = *reinterpret_cast<const float4*>(base);
        float bv0 = v.x, bv1 = v.y, bv2 = v.z, bv3 = v.w;
        int bi0 = 0, bi1 = 0, bi2 = 0, bi3 = 0;

#pragma unroll
        for (int c = 1; c < NUM_CLASSES; ++c) {
            float4 w = *reinterpret_cast<const float4*>(base + (size_t)c * HW);
            if (w.x > bv0) { bv0 = w.x; bi0 = c; }   // strict > keeps first max (jnp.argmax)
            if (w.y > bv1) { bv1 = w.y; bi1 = c; }
            if (w.z > bv2) { bv2 = w.z; bi2 = c; }
            if (w.w > bv3) { bv3 = w.w; bi3 = c; }
        }

        int4 t = *reinterpret_cast<const int4*>(target + p);

        atomicAdd(&s_pred[bi0], 1u);
        atomicAdd(&s_pred[bi1], 1u);
        atomicAdd(&s_pred[bi2], 1u);
        atomicAdd(&s_pred[bi3], 1u);

        atomicAdd(&s_tgt[t.x], 1u);
        atomicAdd(&s_tgt[t.y], 1u);
        atomicAdd(&s_tgt[t.z], 1u);
        atomicAdd(&s_tgt[t.w], 1u);

        if (bi0 == t.x) atomicAdd(&s_inter[bi0], 1u);
        if (bi1 == t.y) atomicAdd(&s_inter[bi1], 1u);
        if (bi2 == t.z) atomicAdd(&s_inter[bi2], 1u);
        if (bi3 == t.w) atomicAdd(&s_inter[bi3], 1u);
    }

    __syncthreads();
    if (tid < NUM_CLASSES) {
        unsigned int cp = s_pred[tid];
        unsigned int ct = s_tgt[tid];
        unsigned int ci = s_inter[tid];
        if (cp) atomicAdd(&counts[tid], cp);
        if (ct) atomicAdd(&counts[NUM_CLASSES + tid], ct);
        if (ci) atomicAdd(&counts[2 * NUM_CLASSES + tid], ci);
    }
}

__global__ void iou_finalize_kernel(const unsigned int* __restrict__ counts,
                                    float* __restrict__ out) {
    const int c = threadIdx.x;
    float iou = 0.0f;
    if (c < NUM_CLASSES) {
        float inter = (float)counts[2 * NUM_CLASSES + c];
        float uni = (float)counts[c] + (float)counts[NUM_CLASSES + c] - inter;
        iou = (inter + SMOOTH) / (uni + SMOOTH);
    }
#pragma unroll
    for (int off = 32; off > 0; off >>= 1) iou += __shfl_down(iou, off);
    if (c == 0) out[0] = iou * (1.0f / NUM_CLASSES);
}

extern "C" void kernel_launch(void* const* d_in, const int* in_sizes, int n_in,
                              void* d_out, int out_size, void* d_ws, size_t ws_size,
                              hipStream_t stream) {
    const float* pred = (const float*)d_in[0];
    const int* target = (const int*)d_in[1];
    float* out = (float*)d_out;
    unsigned int* counts = (unsigned int*)d_ws;

    hipMemsetAsync(counts, 0, 3 * NUM_CLASSES * sizeof(unsigned int), stream);

    const int nquads = TOTAL_PIX / 4;           // 524288
    const int block = 256;
    const int grid = nquads / block;            // 2048 blocks, 1 quad/thread
    iou_hist_kernel<<<grid, block, 0, stream>>>(pred, target, counts);
    iou_finalize_kernel<<<1, 64, 0, stream>>>(counts, out);
}

// Round 3
// 261.146 us; speedup vs baseline: 1.0171x; 1.0171x over previous
//
#include <hip/hip_runtime.h>

#define NUM_CLASSES 21
#define HW (512 * 512)
#define NBATCH 8
#define TOTAL_PIX (NBATCH * HW)
#define SMOOTH 1e-6f

// counts layout in d_ws (unsigned int):
//  [0 .. 20]   cnt_pred
//  [21 .. 41]  cnt_tgt
//  [42 .. 62]  inter

__global__ void iou_hist_kernel(const float* __restrict__ pred,
                                const int* __restrict__ target,
                                unsigned int* __restrict__ counts) {
    // packed: lo16 = pred count, hi16 = intersection count (block max 1024 < 2^16)
    __shared__ unsigned int s_pi[NUM_CLASSES];
    __shared__ unsigned int s_tgt[NUM_CLASSES];

    const int tid = threadIdx.x;
    if (tid < NUM_CLASSES) {
        s_pi[tid] = 0u;
        s_tgt[tid] = 0u;
    }
    __syncthreads();

    const int q = blockIdx.x * blockDim.x + tid;   // one quad per thread, exact cover
    const int p = q * 4;
    const int b = p / HW;
    const int i = p - b * HW;
    const float* base = pred + (size_t)b * NUM_CLASSES * HW + i;

    // Hoist ALL class loads first: 21 independent 16B loads in flight per lane.
    float4 w[NUM_CLASSES];
#pragma unroll
    for (int c = 0; c < NUM_CLASSES; ++c) {
        w[c] = *reinterpret_cast<const float4*>(base + (size_t)c * HW);
    }

    float bv0 = w[0].x, bv1 = w[0].y, bv2 = w[0].z, bv3 = w[0].w;
    int bi0 = 0, bi1 = 0, bi2 = 0, bi3 = 0;
#pragma unroll
    for (int c = 1; c < NUM_CLASSES; ++c) {
        if (w[c].x > bv0) { bv0 = w[c].x; bi0 = c; }  // strict > == first-max (jnp.argmax)
        if (w[c].y > bv1) { bv1 = w[c].y; bi1 = c; }
        if (w[c].z > bv2) { bv2 = w[c].z; bi2 = c; }
        if (w[c].w > bv3) { bv3 = w[c].w; bi3 = c; }
    }

    int4 t = *reinterpret_cast<const int4*>(target + p);

    // pred-count + intersection fused into one atomic per pixel
    atomicAdd(&s_pi[bi0], 1u + (bi0 == t.x ? 0x10000u : 0u));
    atomicAdd(&s_pi[bi1], 1u + (bi1 == t.y ? 0x10000u : 0u));
    atomicAdd(&s_pi[bi2], 1u + (bi2 == t.z ? 0x10000u : 0u));
    atomicAdd(&s_pi[bi3], 1u + (bi3 == t.w ? 0x10000u : 0u));

    atomicAdd(&s_tgt[t.x], 1u);
    atomicAdd(&s_tgt[t.y], 1u);
    atomicAdd(&s_tgt[t.z], 1u);
    atomicAdd(&s_tgt[t.w], 1u);

    __syncthreads();
    if (tid < NUM_CLASSES) {
        unsigned int pi = s_pi[tid];
        unsigned int ct = s_tgt[tid];
        if (pi & 0xFFFFu) atomicAdd(&counts[tid], pi & 0xFFFFu);
        if (ct) atomicAdd(&counts[NUM_CLASSES + tid], ct);
        if (pi >> 16) atomicAdd(&counts[2 * NUM_CLASSES + tid], pi >> 16);
    }
}

__global__ void iou_finalize_kernel(const unsigned int* __restrict__ counts,
                                    float* __restrict__ out) {
    const int c = threadIdx.x;
    float iou = 0.0f;
    if (c < NUM_CLASSES) {
        float inter = (float)counts[2 * NUM_CLASSES + c];
        float uni = (float)counts[c] + (float)counts[NUM_CLASSES + c] - inter;
        iou = (inter + SMOOTH) / (uni + SMOOTH);
    }
#pragma unroll
    for (int off = 32; off > 0; off >>= 1) iou += __shfl_down(iou, off);
    if (c == 0) out[0] = iou * (1.0f / NUM_CLASSES);
}

extern "C" void kernel_launch(void* const* d_in, const int* in_sizes, int n_in,
                              void* d_out, int out_size, void* d_ws, size_t ws_size,
                              hipStream_t stream) {
    const float* pred = (const float*)d_in[0];
    const int* target = (const int*)d_in[1];
    float* out = (float*)d_out;
    unsigned int* counts = (unsigned int*)d_ws;

    hipMemsetAsync(counts, 0, 3 * NUM_CLASSES * sizeof(unsigned int), stream);

    const int nquads = TOTAL_PIX / 4;           // 524288
    const int block = 256;
    const int grid = nquads / block;            // 2048 blocks, exactly 1 quad/thread
    iou_hist_kernel<<<grid, block, 0, stream>>>(pred, target, counts);
    iou_finalize_kernel<<<1, 64, 0, stream>>>(counts, out);
}

// Round 4
// 245.452 us; speedup vs baseline: 1.0822x; 1.0639x over previous
//
#include <hip/hip_runtime.h>

#define NUM_CLASSES 21
#define HW (512 * 512)            // 2^18
#define NBATCH 8
#define TOTAL_PIX (NBATCH * HW)   // 2^21
#define SMOOTH 1e-6f
#define NBLK 4096                 // hist blocks: 2 px/thread, 256 thr -> 512 px/block

// d_ws layout (u32): part[3][NUM_CLASSES][NBLK]  (row 0=pred,1=tgt,2=inter)
//                    then float iou_parts[NUM_CLASSES]
// No zero-init needed: every slot we read is unconditionally written first.

__global__ __launch_bounds__(256) void iou_hist(const float* __restrict__ pred,
                                                const int* __restrict__ target,
                                                unsigned int* __restrict__ part) {
    __shared__ unsigned int s_pi[NUM_CLASSES];   // lo16 = pred count, hi16 = inter (block max 512)
    __shared__ unsigned int s_tgt[NUM_CLASSES];

    const int tid = threadIdx.x;
    if (tid < NUM_CLASSES) { s_pi[tid] = 0u; s_tgt[tid] = 0u; }
    __syncthreads();

    const int q = blockIdx.x * 256 + tid;     // exact cover: 4096*256*2 = 2^21 px
    const int p = q * 2;
    const int b = p >> 18;                    // HW = 2^18
    const int i = p & (HW - 1);
    const float* base = pred + (((size_t)b * NUM_CLASSES) << 18) + i;

    float2 w[NUM_CLASSES];
#pragma unroll
    for (int c = 0; c < NUM_CLASSES; ++c)
        w[c] = *reinterpret_cast<const float2*>(base + ((size_t)c << 18));

    float bv0 = w[0].x, bv1 = w[0].y;
    int bi0 = 0, bi1 = 0;
#pragma unroll
    for (int c = 1; c < NUM_CLASSES; ++c) {
        if (w[c].x > bv0) { bv0 = w[c].x; bi0 = c; }   // strict > == first-max (jnp.argmax)
        if (w[c].y > bv1) { bv1 = w[c].y; bi1 = c; }
    }

    int2 t = *reinterpret_cast<const int2*>(target + p);

    atomicAdd(&s_pi[bi0], 1u + (bi0 == t.x ? 0x10000u : 0u));
    atomicAdd(&s_pi[bi1], 1u + (bi1 == t.y ? 0x10000u : 0u));
    atomicAdd(&s_tgt[t.x], 1u);
    atomicAdd(&s_tgt[t.y], 1u);

    __syncthreads();
    if (tid < NUM_CLASSES) {
        unsigned int pi = s_pi[tid];
        // plain stores, class-major so reduce reads are contiguous — NO global atomics
        part[(0 * NUM_CLASSES + tid) * NBLK + blockIdx.x] = pi & 0xFFFFu;
        part[(1 * NUM_CLASSES + tid) * NBLK + blockIdx.x] = s_tgt[tid];
        part[(2 * NUM_CLASSES + tid) * NBLK + blockIdx.x] = pi >> 16;
    }
}

__global__ __launch_bounds__(256) void iou_reduce1(const unsigned int* __restrict__ part,
                                                   float* __restrict__ iou_parts) {
    const int c = blockIdx.x;                 // one class per block
    const int tid = threadIdx.x;
    const uint4* p0 = reinterpret_cast<const uint4*>(part + (0 * NUM_CLASSES + c) * NBLK);
    const uint4* p1 = reinterpret_cast<const uint4*>(part + (1 * NUM_CLASSES + c) * NBLK);
    const uint4* p2 = reinterpret_cast<const uint4*>(part + (2 * NUM_CLASSES + c) * NBLK);

    unsigned int s0 = 0, s1 = 0, s2 = 0;
#pragma unroll
    for (int k = tid; k < NBLK / 4; k += 256) {   // 1024 uint4 per row, 4 per thread
        uint4 a = p0[k]; s0 += a.x + a.y + a.z + a.w;
        uint4 bb = p1[k]; s1 += bb.x + bb.y + bb.z + bb.w;
        uint4 d = p2[k]; s2 += d.x + d.y + d.z + d.w;
    }
#pragma unroll
    for (int off = 32; off > 0; off >>= 1) {
        s0 += __shfl_down(s0, off);
        s1 += __shfl_down(s1, off);
        s2 += __shfl_down(s2, off);
    }
    __shared__ unsigned int ls[3][4];
    const int w = tid >> 6, lane = tid & 63;
    if (lane == 0) { ls[0][w] = s0; ls[1][w] = s1; ls[2][w] = s2; }
    __syncthreads();
    if (tid == 0) {
        unsigned int t0 = ls[0][0] + ls[0][1] + ls[0][2] + ls[0][3];
        unsigned int t1 = ls[1][0] + ls[1][1] + ls[1][2] + ls[1][3];
        unsigned int t2 = ls[2][0] + ls[2][1] + ls[2][2] + ls[2][3];
        float inter = (float)t2;
        float uni = (float)t0 + (float)t1 - inter;
        iou_parts[c] = (inter + SMOOTH) / (uni + SMOOTH);
    }
}

__global__ void iou_reduce2(const float* __restrict__ iou_parts, float* __restrict__ out) {
    float v = threadIdx.x < NUM_CLASSES ? iou_parts[threadIdx.x] : 0.0f;
#pragma unroll
    for (int off = 32; off > 0; off >>= 1) v += __shfl_down(v, off);
    if (threadIdx.x == 0) out[0] = v * (1.0f / NUM_CLASSES);
}

extern "C" void kernel_launch(void* const* d_in, const int* in_sizes, int n_in,
                              void* d_out, int out_size, void* d_ws, size_t ws_size,
                              hipStream_t stream) {
    const float* pred = (const float*)d_in[0];
    const int* target = (const int*)d_in[1];
    float* out = (float*)d_out;

    unsigned int* part = (unsigned int*)d_ws;
    float* iou_parts = (float*)(part + 3 * NUM_CLASSES * NBLK);

    iou_hist<<<NBLK, 256, 0, stream>>>(pred, target, part);
    iou_reduce1<<<NUM_CLASSES, 256, 0, stream>>>(part, iou_parts);
    iou_reduce2<<<1, 64, 0, stream>>>(iou_parts, out);
}